// Round 1
// baseline (603.910 us; speedup 1.0000x reference)
//
#include <hip/hip_runtime.h>
#include <math.h>

#define B 64
#define S 1024
#define H 512
#define OUT 256
#define STEPS 32
#define NG 2048   // 4*H
#define X 768     // OUT + H

__device__ __forceinline__ float sigf(float x) { return 1.0f / (1.0f + __expf(-x)); }

// ---------------- context: flash softmax-weighted sum over S ----------------
// grid (8 chunks, 64 b), 256 thr (4 waves). Each wave: online softmax over its s's.
__global__ __launch_bounds__(256) void k_ctx_partial(
    const float* __restrict__ enc, const float* __restrict__ attn_w,
    float* __restrict__ part_ctx, float* __restrict__ part_ml) {
  const int b = blockIdx.y, chunk = blockIdx.x;
  const int wave = threadIdx.x >> 6, lane = threadIdx.x & 63;
  const float4 wa0 = *(const float4*)(attn_w + lane * 8);
  const float4 wa1 = *(const float4*)(attn_w + lane * 8 + 4);
  const float* eb = enc + (long)b * S * H;
  float m = -1e30f, l = 0.0f;
  float acc[8];
#pragma unroll
  for (int r = 0; r < 8; ++r) acc[r] = 0.0f;
  for (int i = 0; i < 32; ++i) {
    const int s = chunk * 128 + i * 4 + wave;
    const float* row = eb + (long)s * H + lane * 8;
    const float4 v0 = *(const float4*)row;
    const float4 v1 = *(const float4*)(row + 4);
    float e = v0.x * wa0.x + v0.y * wa0.y + v0.z * wa0.z + v0.w * wa0.w +
              v1.x * wa1.x + v1.y * wa1.y + v1.z * wa1.z + v1.w * wa1.w;
#pragma unroll
    for (int msk = 1; msk < 64; msk <<= 1) e += __shfl_xor(e, msk, 64);
    const float mn = fmaxf(m, e);
    const float sc = __expf(m - mn);
    const float p = __expf(e - mn);
    l = l * sc + p;
    m = mn;
    acc[0] = acc[0] * sc + p * v0.x; acc[1] = acc[1] * sc + p * v0.y;
    acc[2] = acc[2] * sc + p * v0.z; acc[3] = acc[3] * sc + p * v0.w;
    acc[4] = acc[4] * sc + p * v1.x; acc[5] = acc[5] * sc + p * v1.y;
    acc[6] = acc[6] * sc + p * v1.z; acc[7] = acc[7] * sc + p * v1.w;
  }
  __shared__ float sm_acc[4][H];
  __shared__ float sm_m[4], sm_l[4];
#pragma unroll
  for (int r = 0; r < 8; ++r) sm_acc[wave][lane * 8 + r] = acc[r];
  if (lane == 0) { sm_m[wave] = m; sm_l[wave] = l; }
  __syncthreads();
  const float mb = fmaxf(fmaxf(sm_m[0], sm_m[1]), fmaxf(sm_m[2], sm_m[3]));
  float e0[4];
#pragma unroll
  for (int w = 0; w < 4; ++w) e0[w] = __expf(sm_m[w] - mb);
  const int h0 = threadIdx.x * 2;
  float s0 = 0.f, s1 = 0.f;
#pragma unroll
  for (int w = 0; w < 4; ++w) { s0 += sm_acc[w][h0] * e0[w]; s1 += sm_acc[w][h0 + 1] * e0[w]; }
  float* pc = part_ctx + ((long)chunk * B + b) * H;
  pc[h0] = s0; pc[h0 + 1] = s1;
  if (threadIdx.x == 0) {
    const float lb = sm_l[0] * e0[0] + sm_l[1] * e0[1] + sm_l[2] * e0[2] + sm_l[3] * e0[3];
    part_ml[(chunk * B + b) * 2] = mb;
    part_ml[(chunk * B + b) * 2 + 1] = lb;
  }
}

// grid 64 (one per b), 256 thr: combine 8 chunk partials, normalize.
__global__ __launch_bounds__(256) void k_ctx_reduce(
    const float* __restrict__ part_ctx, const float* __restrict__ part_ml,
    float* __restrict__ ctx) {
  const int b = blockIdx.x;
  float m = -1e30f;
#pragma unroll
  for (int c = 0; c < 8; ++c) m = fmaxf(m, part_ml[(c * B + b) * 2]);
  float L = 0.f, sc[8];
#pragma unroll
  for (int c = 0; c < 8; ++c) {
    sc[c] = __expf(part_ml[(c * B + b) * 2] - m);
    L += part_ml[(c * B + b) * 2 + 1] * sc[c];
  }
  const float inv = 1.0f / L;
  const int h0 = threadIdx.x * 2;
  float s0 = 0.f, s1 = 0.f;
#pragma unroll
  for (int c = 0; c < 8; ++c) {
    const float* pc = part_ctx + ((long)c * B + b) * H;
    s0 += pc[h0] * sc[c]; s1 += pc[h0 + 1] * sc[c];
  }
  ctx[(long)b * H + h0] = s0 * inv;
  ctx[(long)b * H + h0 + 1] = s1 * inv;
}

// ---------------- Weff = w_hh + Wd @ fc_w  (2048 x 512) ----------------
// grid 1024, 256 thr; each thread one float4 of output.
__global__ __launch_bounds__(256) void k_weff(
    const float* __restrict__ w_ih, const float* __restrict__ w_hh,
    const float* __restrict__ fc_w, float* __restrict__ weff) {
  const int flat4 = blockIdx.x * 256 + threadIdx.x;  // 0..262143
  const int n = flat4 >> 7;
  const int k = (flat4 & 127) << 2;
  const float* wd = w_ih + (long)n * X;  // first OUT entries = Wd row
  float ax = 0.f, ay = 0.f, az = 0.f, aw = 0.f;
  for (int j = 0; j < OUT; ++j) {
    const float w = wd[j];
    const float4 f = *(const float4*)(fc_w + (long)j * H + k);
    ax = fmaf(w, f.x, ax); ay = fmaf(w, f.y, ay);
    az = fmaf(w, f.z, az); aw = fmaf(w, f.w, aw);
  }
  const float4 hh = *(const float4*)(w_hh + (long)n * H + k);
  float4 o; o.x = ax + hh.x; o.y = ay + hh.y; o.z = az + hh.z; o.w = aw + hh.w;
  *(float4*)(weff + (long)n * H + k) = o;
}

// ---------------- gbase / gbase2 ----------------
// gbase[b,n]  = b_ih[n]+b_hh[n] + Wc[n,:]·ctx[b,:]
// gbase2[b,n] = gbase[b,n] + Wd[n,:]·fc_b
// grid (128 n-tiles of 16, 4 b-quads of 16), 256 thr (n fastest).
__global__ __launch_bounds__(256) void k_gbase(
    const float* __restrict__ w_ih, const float* __restrict__ b_ih,
    const float* __restrict__ b_hh, const float* __restrict__ fc_b,
    const float* __restrict__ ctx, float* __restrict__ gbase,
    float* __restrict__ gbase2) {
  __shared__ float lctx[16][H + 4];
  const int nt = blockIdx.x, bq = blockIdx.y;
  for (int i = threadIdx.x; i < 16 * 128; i += 256) {
    const int bb = i >> 7, kk = (i & 127) << 2;
    *(float4*)&lctx[bb][kk] = *(const float4*)(ctx + (long)(bq * 16 + bb) * H + kk);
  }
  __syncthreads();
  const int n_l = threadIdx.x & 15, b_l = threadIdx.x >> 4;
  const int n = nt * 16 + n_l;
  const float* wr = w_ih + (long)n * X;
  float acc = 0.f;
  for (int k = 0; k < H; k += 4) {
    const float4 c4 = *(float4*)&lctx[b_l][k];
    const float4 w4 = *(const float4*)(wr + OUT + k);
    acc += c4.x * w4.x + c4.y * w4.y + c4.z * w4.z + c4.w * w4.w;
  }
  float db = 0.f;
  for (int j = 0; j < OUT; j += 4) {
    const float4 w4 = *(const float4*)(wr + j);
    const float4 f4v = *(const float4*)(fc_b + j);
    db += w4.x * f4v.x + w4.y * f4v.y + w4.z * f4v.z + w4.w * f4v.w;
  }
  const float g = acc + b_ih[n] + b_hh[n];
  const int b = bq * 16 + b_l;
  gbase[(long)b * NG + n] = g;
  gbase2[(long)b * NG + n] = g + db;
}

// ---------------- one LSTM step: gates = h@W^T + gb, fused cell ----------------
// grid (128 j-tiles of 4, 4 b-quads of 16), 256 thr = 16 b x 4 j x 4 k-quarters.
template <bool FIRST>
__global__ __launch_bounds__(256) void k_step(
    const float* __restrict__ h_in, const float* __restrict__ W,
    const float* __restrict__ gb, float* __restrict__ c,
    float* __restrict__ h_out) {
  __shared__ float lh[16][H + 4];
  __shared__ float red[64][3][4];
  const int jt = blockIdx.x, bq = blockIdx.y;
  for (int i = threadIdx.x; i < 16 * 128; i += 256) {
    const int bb = i >> 7, kk = (i & 127) << 2;
    *(float4*)&lh[bb][kk] = *(const float4*)(h_in + (long)(bq * 16 + bb) * H + kk);
  }
  __syncthreads();
  const int b_l = threadIdx.x & 15;
  const int j_l = (threadIdx.x >> 4) & 3;
  const int ks = threadIdx.x >> 6;
  const int cell = threadIdx.x & 63;
  const int col = jt * 4 + j_l;
  const float* w0 = W + (long)col * H;
  const float* w1 = W + (long)(col + 512) * H;
  const float* w2 = W + (long)(col + 1024) * H;
  const float* w3 = W + (long)(col + 1536) * H;
  float a0 = 0.f, a1 = 0.f, a2 = 0.f, a3 = 0.f;
  const int k0 = ks * 128;
  for (int k = k0; k < k0 + 128; k += 4) {
    const float4 hv = *(float4*)&lh[b_l][k];
    const float4 x0 = *(const float4*)(w0 + k);
    const float4 x1 = *(const float4*)(w1 + k);
    const float4 x2 = *(const float4*)(w2 + k);
    const float4 x3 = *(const float4*)(w3 + k);
    a0 = fmaf(hv.x, x0.x, fmaf(hv.y, x0.y, fmaf(hv.z, x0.z, fmaf(hv.w, x0.w, a0))));
    a1 = fmaf(hv.x, x1.x, fmaf(hv.y, x1.y, fmaf(hv.z, x1.z, fmaf(hv.w, x1.w, a1))));
    a2 = fmaf(hv.x, x2.x, fmaf(hv.y, x2.y, fmaf(hv.z, x2.z, fmaf(hv.w, x2.w, a2))));
    a3 = fmaf(hv.x, x3.x, fmaf(hv.y, x3.y, fmaf(hv.z, x3.z, fmaf(hv.w, x3.w, a3))));
  }
  if (ks > 0) {
    red[cell][ks - 1][0] = a0; red[cell][ks - 1][1] = a1;
    red[cell][ks - 1][2] = a2; red[cell][ks - 1][3] = a3;
  }
  __syncthreads();
  if (ks == 0) {
    const int b = bq * 16 + b_l;
    const float* g0 = gb + (long)b * NG + col;
    float gi = a0 + red[cell][0][0] + red[cell][1][0] + red[cell][2][0] + g0[0];
    float gf = a1 + red[cell][0][1] + red[cell][1][1] + red[cell][2][1] + g0[512];
    float gg = a2 + red[cell][0][2] + red[cell][1][2] + red[cell][2][2] + g0[1024];
    float go = a3 + red[cell][0][3] + red[cell][1][3] + red[cell][2][3] + g0[1536];
    const float c_old = FIRST ? 0.f : c[(long)b * H + col];
    const float cn = sigf(gf) * c_old + sigf(gi) * tanhf(gg);
    const float hn = sigf(go) * tanhf(cn);
    c[(long)b * H + col] = cn;
    h_out[(long)b * H + col] = hn;
  }
}

// ---------------- final: out[b,t,:] = hs[t][b,:] @ fc_w^T + fc_b ----------------
// grid (8 t-tiles of 4, 64 b), 256 thr = 4 t x 64 o-groups of 4.
__global__ __launch_bounds__(256) void k_dec(
    const float* __restrict__ hs, const float* __restrict__ fc_w,
    const float* __restrict__ fc_b, float* __restrict__ out) {
  __shared__ float lhd[4][H + 4];
  const int tq = blockIdx.x, b = blockIdx.y;
  for (int i = threadIdx.x; i < 4 * 128; i += 256) {
    const int tt = i >> 7, kk = (i & 127) << 2;
    *(float4*)&lhd[tt][kk] =
        *(const float4*)(hs + ((long)(tq * 4 + tt) * B + b) * H + kk);
  }
  __syncthreads();
  const int t_l = threadIdx.x >> 6;
  const int og = threadIdx.x & 63;
  const int o0 = og * 4;
  float a0 = 0.f, a1 = 0.f, a2 = 0.f, a3 = 0.f;
  for (int k = 0; k < H; k += 4) {
    const float4 hv = *(float4*)&lhd[t_l][k];
    const float4 r0 = *(const float4*)(fc_w + (long)(o0 + 0) * H + k);
    const float4 r1 = *(const float4*)(fc_w + (long)(o0 + 1) * H + k);
    const float4 r2 = *(const float4*)(fc_w + (long)(o0 + 2) * H + k);
    const float4 r3 = *(const float4*)(fc_w + (long)(o0 + 3) * H + k);
    a0 = fmaf(hv.x, r0.x, fmaf(hv.y, r0.y, fmaf(hv.z, r0.z, fmaf(hv.w, r0.w, a0))));
    a1 = fmaf(hv.x, r1.x, fmaf(hv.y, r1.y, fmaf(hv.z, r1.z, fmaf(hv.w, r1.w, a1))));
    a2 = fmaf(hv.x, r2.x, fmaf(hv.y, r2.y, fmaf(hv.z, r2.z, fmaf(hv.w, r2.w, a2))));
    a3 = fmaf(hv.x, r3.x, fmaf(hv.y, r3.y, fmaf(hv.z, r3.z, fmaf(hv.w, r3.w, a3))));
  }
  const float4 fb = *(const float4*)(fc_b + o0);
  float4 o;
  o.x = a0 + fb.x; o.y = a1 + fb.y; o.z = a2 + fb.z; o.w = a3 + fb.w;
  *(float4*)(out + ((long)b * STEPS + tq * 4 + t_l) * OUT + o0) = o;
}

extern "C" void kernel_launch(void* const* d_in, const int* in_sizes, int n_in,
                              void* d_out, int out_size, void* d_ws, size_t ws_size,
                              hipStream_t stream) {
  const float* enc = (const float*)d_in[0];
  const float* hidden = (const float*)d_in[1];
  const float* attn_w = (const float*)d_in[2];
  // d_in[3] = attn_b: constant shift along softmax axis -> provably irrelevant.
  const float* w_ih = (const float*)d_in[4];
  const float* w_hh = (const float*)d_in[5];
  const float* b_ih = (const float*)d_in[6];
  const float* b_hh = (const float*)d_in[7];
  const float* fc_w = (const float*)d_in[8];
  const float* fc_b = (const float*)d_in[9];
  float* out = (float*)d_out;

  float* ws = (float*)d_ws;
  float* ctx      = ws;                  // 32768
  float* part_ctx = ctx + 32768;         // 262144
  float* part_ml  = part_ctx + 262144;   // 1024
  float* weff     = part_ml + 1024;      // 1048576
  float* gbase    = weff + 1048576;      // 131072
  float* gbase2   = gbase + 131072;      // 131072
  float* hs       = gbase2 + 131072;     // 32*32768 = 1048576
  float* cbuf     = hs + 1048576;        // 32768
  // total 2,688,000 floats ~= 10.3 MB

  k_ctx_partial<<<dim3(8, 64), 256, 0, stream>>>(enc, attn_w, part_ctx, part_ml);
  k_weff<<<1024, 256, 0, stream>>>(w_ih, w_hh, fc_w, weff);
  k_ctx_reduce<<<64, 256, 0, stream>>>(part_ctx, part_ml, ctx);
  k_gbase<<<dim3(128, 4), 256, 0, stream>>>(w_ih, b_ih, b_hh, fc_b, ctx, gbase, gbase2);

  k_step<true><<<dim3(128, 4), 256, 0, stream>>>(hidden, w_hh, gbase, cbuf, hs);
  for (int t = 1; t < STEPS; ++t) {
    k_step<false><<<dim3(128, 4), 256, 0, stream>>>(hs + (long)(t - 1) * 32768, weff,
                                                    gbase2, cbuf, hs + (long)t * 32768);
  }
  k_dec<<<dim3(8, 64), 256, 0, stream>>>(hs, fc_w, fc_b, out);
}